// Round 9
// baseline (412.463 us; speedup 1.0000x reference)
//
#include <hip/hip_runtime.h>
#include <hip/hip_bf16.h>
#include <math.h>

#define BSHIFT 7                 // 128 nodes per bucket
#define NBUCK(N) (((N) + 127) >> 7)
#define TILE 8192                // edges per partition block (R0 proven: 103 us)
#define CAP 5632                 // max edges/bucket (mean 4224, sd ~65 -> ~21 sigma)

typedef short bf16x8 __attribute__((ext_vector_type(8)));
typedef float f32x16 __attribute__((ext_vector_type(16)));

// ---- bf16 helpers ---------------------------------------------------------
__device__ __forceinline__ unsigned short f2bf(float f) {
    unsigned u = __float_as_uint(f);
    u += 0x7fffu + ((u >> 16) & 1u);      // RNE
    return (unsigned short)(u >> 16);
}
__device__ __forceinline__ unsigned packbf2(float lo, float hi) {
    return (unsigned)f2bf(lo) | ((unsigned)f2bf(hi) << 16);
}
__device__ __forceinline__ float bf_lo(unsigned u) { return __uint_as_float(u << 16); }
__device__ __forceinline__ float bf_hi(unsigned u) { return __uint_as_float(u & 0xffff0000u); }

// ---- pg: part (blocks < PB) fused with gemm1 (blocks >= PB) ---------------
// R9: src-side pipeline (cS/bS histograms, gbufS byte-scatter, fillS kernel)
// replaced by ONE fire-and-forget global atomicAdd per edge into the 400KB
// L2-resident outdeg array (~33 hits/addr). R1/R2 tested this confounded by
// a VGPR-16 scratch spill; this keeps the register-healthy R0 skeleton
// (dv[32], 256thr, phase-3 src reload, VGPR ~68) with exactly that one edit.
// Phase 3 is now half the work (one LDS atomic + one 4B scatter per edge).
__global__ __launch_bounds__(256) void pg_kernel(
    const int* __restrict__ src, const int* __restrict__ dst,
    int* __restrict__ gcurD, int* __restrict__ outdeg,
    int* __restrict__ gbufD,
    const float* __restrict__ feat, const float* __restrict__ W1,
    unsigned short* __restrict__ h1, int E, int K, int PB, int N) {
    __shared__ char smem[16896];   // max(part 6.4 KB, gemm W1t 16.9 KB)
    const int t = threadIdx.x;

    if (blockIdx.x < PB) {
        // ---------------- part body ----------------
        int* cD = (int*)smem;
        int* bD = cD + 800;        // 1600 ints = 6.4 KB
        const int tile = blockIdx.x * TILE;
        for (int i = t; i < K; i += 256) cD[i] = 0;
        __syncthreads();

        int dv[32];
        #pragma unroll
        for (int i = 0; i < 32; ++i) {
            const int e = tile + i * 256 + t;
            dv[i] = (e < E) ? dst[e] : -1;
            if (dv[i] >= 0) {
                atomicAdd(&cD[dv[i] >> BSHIFT], 1);
                atomicAdd(&outdeg[src[e]], 1);   // fire-and-forget, no return
            }
        }
        __syncthreads();
        for (int i = t; i < K; i += 256) {
            const int c = cD[i];
            bD[i] = (c ? atomicAdd(&gcurD[i], c) : 0) + i * CAP;
            cD[i] = 0;
        }
        __syncthreads();
        #pragma unroll
        for (int i = 0; i < 32; ++i) {
            if (dv[i] >= 0) {
                const int e = tile + i * 256 + t;
                const int sv = src[e];
                const int b1 = dv[i] >> BSHIFT;
                const int p1 = bD[b1] + atomicAdd(&cD[b1], 1);
                gbufD[p1] = ((dv[i] & 127) << 17) | sv;
            }
        }
    } else {
        // ---------------- gemm1 body (unscaled h1) -------------------------
        short* W1t = (short*)smem;     // W1t[c][k] = bf16(W1[k][c]), stride 264
        for (int i = t; i < 8192; i += 256) {
            const int k = i >> 5, c = i & 31;
            W1t[c * 264 + k] = (short)f2bf(W1[i]);
        }
        __syncthreads();

        const int l  = t & 63;
        const int wv = t >> 6;
        const int base = (blockIdx.x - PB) * 128 + wv * 32;
        const int m  = l & 31;
        const int kh = (l >> 5) << 3;
        int r = base + m;
        if (r >= N) r = N - 1;
        const float* fr = feat + (size_t)r * 256 + kh;
        const short* wr = &W1t[m * 264 + kh];

        f32x16 acc;
        #pragma unroll
        for (int i = 0; i < 16; ++i) acc[i] = 0.f;

        #pragma unroll
        for (int kb = 0; kb < 16; ++kb) {
            const float4 f0 = *(const float4*)(fr + kb * 16);
            const float4 f1 = *(const float4*)(fr + kb * 16 + 4);
            bf16x8 a;
            a[0] = (short)f2bf(f0.x); a[1] = (short)f2bf(f0.y);
            a[2] = (short)f2bf(f0.z); a[3] = (short)f2bf(f0.w);
            a[4] = (short)f2bf(f1.x); a[5] = (short)f2bf(f1.y);
            a[6] = (short)f2bf(f1.z); a[7] = (short)f2bf(f1.w);
            const bf16x8 b = *(const bf16x8*)(wr + kb * 16);
            acc = __builtin_amdgcn_mfma_f32_32x32x16_bf16(a, b, acc, 0, 0, 0);
        }

        const int rbase = base + ((l >> 5) << 2);
        #pragma unroll
        for (int reg = 0; reg < 16; ++reg) {
            const int row = rbase + (reg & 3) + ((reg >> 2) << 3);
            if (row < N)
                h1[(size_t)row * 32 + m] = f2bf(acc[reg]);
        }
    }
}

// ---- fda1: fillD + agg1 fused, one 512-thread block per dst-bucket --------
// LDS sort (count/scan/scatter), CSR dumped in place over gbufD segment,
// then gather-aggregate from LDS-resident CSR (4 lanes/node, unroll-4).
// nsrc is consumed as rsqrtf(outdeg) inline (bitwise-identical to fillS's
// stored value; ~13M v_rsq total = ~0.1 us).
__global__ __launch_bounds__(512) void fda1_kernel(
    const int* __restrict__ cntD, int* __restrict__ gbufD,
    const unsigned* __restrict__ h1, const int* __restrict__ outdeg,
    const float* __restrict__ b1, int* __restrict__ rowstart,
    int* __restrict__ indeg, float* __restrict__ ndst,
    unsigned* __restrict__ x1s, int N, int K) {
    __shared__ int lraw[CAP];          // 22.5 KB
    __shared__ int lcsr[CAP];          // 22.5 KB
    __shared__ int cnt[128], sc[128], cur[128];
    __shared__ float sb1[32];
    const int t = threadIdx.x;
    const int b = blockIdx.x;
    if (t < 128) cnt[t] = 0;
    if (t >= 128 && t < 160) sb1[t - 128] = b1[t - 128];
    __syncthreads();

    const int bs = b * CAP;
    const int total = min(cntD[b], CAP);   // defensive clamp (LDS bounds)
    for (int i = t; i < total; i += 512) {
        const int v = gbufD[bs + i];
        lraw[i] = v;
        atomicAdd(&cnt[v >> 17], 1);
    }
    __syncthreads();
    if (t < 128) sc[t] = cnt[t];
    __syncthreads();
    for (int off = 1; off < 128; off <<= 1) {
        int x = (t < 128 && t >= off) ? sc[t - off] : 0;
        __syncthreads();
        if (t < 128) sc[t] += x;
        __syncthreads();
    }
    if (t < 128) {
        const int deg = cnt[t];
        cur[t] = sc[t] - deg;          // bucket-local
        const int n = (b << BSHIFT) + t;
        if (n < N) {
            rowstart[n] = bs + sc[t] - deg;
            indeg[n] = deg;
            ndst[n] = rsqrtf((float)deg);   // self-loops => deg >= 1
        }
    }
    __syncthreads();
    for (int i = t; i < total; i += 512) {
        const int v = lraw[i];
        const int pos = atomicAdd(&cur[v >> 17], 1);
        lcsr[pos] = v & 131071;
    }
    __syncthreads();
    // dump sorted CSR for agg2f, in place over this bucket's gbufD segment
    for (int i = t; i < total; i += 512) gbufD[bs + i] = lcsr[i];

    // ---- agg1 from LDS csr: 4 lanes per node ----
    const int node = t >> 2;
    const int c = t & 3;
    const int n = (b << BSHIFT) + node;
    if (n >= N) return;
    const int deg = cnt[node];
    const int re = sc[node];
    int k = re - deg;
    float a0=0.f,a1=0.f,a2=0.f,a3=0.f,a4=0.f,a5=0.f,a6=0.f,a7=0.f;
    float d0=0.f,d1=0.f,d2=0.f,d3=0.f,d4=0.f,d5=0.f,d6=0.f,d7=0.f;
    const uint4* H = (const uint4*)h1;
    for (; k + 3 < re; k += 4) {
        const int s0 = lcsr[k],     s1 = lcsr[k + 1];
        const int s2 = lcsr[k + 2], s3 = lcsr[k + 3];
        const uint4 q0 = H[(size_t)s0 * 4 + c];
        const uint4 q1 = H[(size_t)s1 * 4 + c];
        const uint4 q2 = H[(size_t)s2 * 4 + c];
        const uint4 q3 = H[(size_t)s3 * 4 + c];
        const float w0 = rsqrtf((float)outdeg[s0]);
        const float w1 = rsqrtf((float)outdeg[s1]);
        const float w2 = rsqrtf((float)outdeg[s2]);
        const float w3 = rsqrtf((float)outdeg[s3]);
        a0 += bf_lo(q0.x)*w0; a1 += bf_hi(q0.x)*w0;
        a2 += bf_lo(q0.y)*w0; a3 += bf_hi(q0.y)*w0;
        a4 += bf_lo(q0.z)*w0; a5 += bf_hi(q0.z)*w0;
        a6 += bf_lo(q0.w)*w0; a7 += bf_hi(q0.w)*w0;
        d0 += bf_lo(q1.x)*w1; d1 += bf_hi(q1.x)*w1;
        d2 += bf_lo(q1.y)*w1; d3 += bf_hi(q1.y)*w1;
        d4 += bf_lo(q1.z)*w1; d5 += bf_hi(q1.z)*w1;
        d6 += bf_lo(q1.w)*w1; d7 += bf_hi(q1.w)*w1;
        a0 += bf_lo(q2.x)*w2; a1 += bf_hi(q2.x)*w2;
        a2 += bf_lo(q2.y)*w2; a3 += bf_hi(q2.y)*w2;
        a4 += bf_lo(q2.z)*w2; a5 += bf_hi(q2.z)*w2;
        a6 += bf_lo(q2.w)*w2; a7 += bf_hi(q2.w)*w2;
        d0 += bf_lo(q3.x)*w3; d1 += bf_hi(q3.x)*w3;
        d2 += bf_lo(q3.y)*w3; d3 += bf_hi(q3.y)*w3;
        d4 += bf_lo(q3.z)*w3; d5 += bf_hi(q3.z)*w3;
        d6 += bf_lo(q3.w)*w3; d7 += bf_hi(q3.w)*w3;
    }
    for (; k < re; ++k) {
        const int s0 = lcsr[k];
        const uint4 q0 = H[(size_t)s0 * 4 + c];
        const float w0 = rsqrtf((float)outdeg[s0]);
        a0 += bf_lo(q0.x)*w0; a1 += bf_hi(q0.x)*w0;
        a2 += bf_lo(q0.y)*w0; a3 += bf_hi(q0.y)*w0;
        a4 += bf_lo(q0.z)*w0; a5 += bf_hi(q0.z)*w0;
        a6 += bf_lo(q0.w)*w0; a7 += bf_hi(q0.w)*w0;
    }
    a0 += d0; a1 += d1; a2 += d2; a3 += d3;
    a4 += d4; a5 += d5; a6 += d6; a7 += d7;
    const float nd = rsqrtf((float)deg);
    const float ns = rsqrtf((float)outdeg[n]);
    const float* bb = sb1 + c * 8;
    float x0 = fmaxf(a0 * nd + bb[0], 0.f) * ns;
    float x1 = fmaxf(a1 * nd + bb[1], 0.f) * ns;
    float x2 = fmaxf(a2 * nd + bb[2], 0.f) * ns;
    float x3 = fmaxf(a3 * nd + bb[3], 0.f) * ns;
    float x4 = fmaxf(a4 * nd + bb[4], 0.f) * ns;
    float x5 = fmaxf(a5 * nd + bb[5], 0.f) * ns;
    float x6 = fmaxf(a6 * nd + bb[6], 0.f) * ns;
    float x7 = fmaxf(a7 * nd + bb[7], 0.f) * ns;
    uint4 o;
    o.x = packbf2(x0, x1); o.y = packbf2(x2, x3);
    o.z = packbf2(x4, x5); o.w = packbf2(x6, x7);
    ((uint4*)x1s)[(size_t)n * 4 + c] = o;
}

// ---- agg2+final fused: z = (ndst[n]*sum x1s[src]) @ W2 + b2; log_softmax --
// Unroll-4: 4 gathers in flight (loop is gather-latency-bound).
__global__ __launch_bounds__(256) void agg2f_kernel(
    const int* __restrict__ csr_src, const int* __restrict__ rowstart,
    const int* __restrict__ indeg, const unsigned* __restrict__ x1s,
    const float* __restrict__ ndst, const float* __restrict__ W2,
    const float* __restrict__ b2, float* __restrict__ out, int N) {
    __shared__ float sW2[32 * 40];
    __shared__ float sb2[40];
    const int t = threadIdx.x;
    for (int i = t; i < 1280; i += 256) sW2[i] = W2[i];
    if (t < 40) sb2[t] = b2[t];
    __syncthreads();
    const int n = blockIdx.x * 64 + (t >> 2);
    if (n >= N) return;
    const int c = t & 3;
    const int rs = rowstart[n];
    const int re = rs + indeg[n];
    float a0=0.f,a1=0.f,a2=0.f,a3=0.f,a4=0.f,a5=0.f,a6=0.f,a7=0.f;
    float d0=0.f,d1=0.f,d2=0.f,d3=0.f,d4=0.f,d5=0.f,d6=0.f,d7=0.f;
    const uint4* H = (const uint4*)x1s;
    int k = rs;
    for (; k + 3 < re; k += 4) {
        const int s0 = csr_src[k],     s1 = csr_src[k + 1];
        const int s2 = csr_src[k + 2], s3 = csr_src[k + 3];
        const uint4 q0 = H[(size_t)s0 * 4 + c];
        const uint4 q1 = H[(size_t)s1 * 4 + c];
        const uint4 q2 = H[(size_t)s2 * 4 + c];
        const uint4 q3 = H[(size_t)s3 * 4 + c];
        a0 += bf_lo(q0.x); a1 += bf_hi(q0.x);
        a2 += bf_lo(q0.y); a3 += bf_hi(q0.y);
        a4 += bf_lo(q0.z); a5 += bf_hi(q0.z);
        a6 += bf_lo(q0.w); a7 += bf_hi(q0.w);
        d0 += bf_lo(q1.x); d1 += bf_hi(q1.x);
        d2 += bf_lo(q1.y); d3 += bf_hi(q1.y);
        d4 += bf_lo(q1.z); d5 += bf_hi(q1.z);
        d6 += bf_lo(q1.w); d7 += bf_hi(q1.w);
        a0 += bf_lo(q2.x); a1 += bf_hi(q2.x);
        a2 += bf_lo(q2.y); a3 += bf_hi(q2.y);
        a4 += bf_lo(q2.z); a5 += bf_hi(q2.z);
        a6 += bf_lo(q2.w); a7 += bf_hi(q2.w);
        d0 += bf_lo(q3.x); d1 += bf_hi(q3.x);
        d2 += bf_lo(q3.y); d3 += bf_hi(q3.y);
        d4 += bf_lo(q3.z); d5 += bf_hi(q3.z);
        d6 += bf_lo(q3.w); d7 += bf_hi(q3.w);
    }
    for (; k < re; ++k) {
        const int s0 = csr_src[k];
        const uint4 q0 = H[(size_t)s0 * 4 + c];
        a0 += bf_lo(q0.x); a1 += bf_hi(q0.x);
        a2 += bf_lo(q0.y); a3 += bf_hi(q0.y);
        a4 += bf_lo(q0.z); a5 += bf_hi(q0.z);
        a6 += bf_lo(q0.w); a7 += bf_hi(q0.w);
    }
    a0 += d0; a1 += d1; a2 += d2; a3 += d3;
    a4 += d4; a5 += d5; a6 += d6; a7 += d7;
    const float nd = ndst[n];
    const float v0 = a0 * nd, v1 = a1 * nd, v2 = a2 * nd, v3 = a3 * nd;
    const float v4 = a4 * nd, v5 = a5 * nd, v6 = a6 * nd, v7 = a7 * nd;

    float z[10];
    #pragma unroll
    for (int u = 0; u < 10; ++u) z[u] = sb2[c * 10 + u];
    const int gbase = (t & 63) & ~3;
    #pragma unroll
    for (int cc = 0; cc < 4; ++cc) {
        const int sl = gbase | cc;
        const float w0 = __shfl(v0, sl, 64);
        const float w1 = __shfl(v1, sl, 64);
        const float w2 = __shfl(v2, sl, 64);
        const float w3 = __shfl(v3, sl, 64);
        const float w4 = __shfl(v4, sl, 64);
        const float w5 = __shfl(v5, sl, 64);
        const float w6 = __shfl(v6, sl, 64);
        const float w7 = __shfl(v7, sl, 64);
        const float* Wr = &sW2[(cc * 8) * 40 + c * 10];
        #pragma unroll
        for (int u = 0; u < 10; ++u) {
            z[u] += w0 * Wr[u]       + w1 * Wr[40 + u]  + w2 * Wr[80 + u]  + w3 * Wr[120 + u]
                  + w4 * Wr[160 + u] + w5 * Wr[200 + u] + w6 * Wr[240 + u] + w7 * Wr[280 + u];
        }
    }
    float m = z[0];
    #pragma unroll
    for (int u = 1; u < 10; ++u) m = fmaxf(m, z[u]);
    m = fmaxf(m, __shfl_xor(m, 1, 64));
    m = fmaxf(m, __shfl_xor(m, 2, 64));
    float s = 0.f;
    #pragma unroll
    for (int u = 0; u < 10; ++u) s += __expf(z[u] - m);
    s += __shfl_xor(s, 1, 64);
    s += __shfl_xor(s, 2, 64);
    const float ls = __logf(s);
    float* op = out + (size_t)n * 40 + c * 10;
    #pragma unroll
    for (int u = 0; u < 10; ++u) op[u] = z[u] - m - ls;
}

extern "C" void kernel_launch(void* const* d_in, const int* in_sizes, int n_in,
                              void* d_out, int out_size, void* d_ws, size_t ws_size,
                              hipStream_t stream) {
    const float* feat = (const float*)d_in[0];
    const int*   src  = (const int*)d_in[1];
    const int*   dst  = (const int*)d_in[2];
    const float* W1   = (const float*)d_in[3];
    const float* b1   = (const float*)d_in[4];
    const float* W2   = (const float*)d_in[5];
    const float* b2   = (const float*)d_in[6];
    float* out = (float*)d_out;

    const int N = in_sizes[0] / 256;   // 100000
    const int E = in_sizes[1];         // 3300000
    const int K = NBUCK(N);            // 782 buckets of 128 nodes

    // layout (~32 MB). outdeg and gcurD adjacent -> one memset.
    //   csr_src == gbufD (same region): fda1 rewrites it in place with
    //   sorted CSR; agg2f reads the sorted version. h1/x1s dedicated.
    char* p = (char*)d_ws;
    int* outdeg   = (int*)p;                 p += (size_t)N * 4;        // 400 KB
    int* gcurD    = (int*)p;                 p += 800 * 4;
    float* ndst   = (float*)p;               p += (size_t)N * 4;
    unsigned* h1  = (unsigned*)p;            p += (size_t)N * 64;       // 6.4 MB
    unsigned* x1s = (unsigned*)p;            p += (size_t)N * 64;       // 6.4 MB
    int* rowstart = (int*)p;                 p += (size_t)N * 4;
    int* indeg_i  = (int*)p;                 p += (size_t)N * 4;
    int* gbufD    = (int*)p;                 p += (size_t)K * CAP * 4;  // 17.6 MB, becomes csr

    hipMemsetAsync(outdeg, 0, (size_t)N * 4 + 800 * 4, stream);   // outdeg + gcurD

    const int PB = (E + TILE - 1) / TILE;      // 403 partition blocks
    const int GB = (N + 127) / 128;            // 782 gemm blocks

    pg_kernel<<<PB + GB, 256, 0, stream>>>(src, dst, gcurD, outdeg, gbufD,
                                           feat, W1, (unsigned short*)h1, E, K, PB, N);
    fda1_kernel<<<K, 512, 0, stream>>>(gcurD, gbufD, h1, outdeg, b1,
                                       rowstart, indeg_i, ndst, x1s, N, K);
    agg2f_kernel<<<(N + 63) / 64, 256, 0, stream>>>(gbufD, rowstart, indeg_i, x1s, ndst, W2, b2, out, N);
}

// Round 10
// 374.337 us; speedup vs baseline: 1.1018x; 1.1018x over previous
//
#include <hip/hip_runtime.h>
#include <hip/hip_bf16.h>
#include <math.h>

#define BSHIFT 7                 // 128 nodes per bucket
#define NBUCK(N) (((N) + 127) >> 7)
#define TILE 8192                // edges per partition block (R0 proven: 103 us)
#define CAP 5632                 // max edges/bucket (mean 4224, sd ~65 -> ~21 sigma)

typedef short bf16x8 __attribute__((ext_vector_type(8)));
typedef float f32x16 __attribute__((ext_vector_type(16)));

// ---- bf16 helpers ---------------------------------------------------------
__device__ __forceinline__ unsigned short f2bf(float f) {
    unsigned u = __float_as_uint(f);
    u += 0x7fffu + ((u >> 16) & 1u);      // RNE
    return (unsigned short)(u >> 16);
}
__device__ __forceinline__ unsigned packbf2(float lo, float hi) {
    return (unsigned)f2bf(lo) | ((unsigned)f2bf(hi) << 16);
}
__device__ __forceinline__ float bf_lo(unsigned u) { return __uint_as_float(u << 16); }
__device__ __forceinline__ float bf_hi(unsigned u) { return __uint_as_float(u & 0xffff0000u); }

// ---- pg: part (blocks < PB) fused with gemm1 (blocks >= PB) ---------------
// EXACT R8 form (384.5 us total). R9 proved per-edge global atomics cost
// +35 us even register-healthy (atomic-rate wall) -> gbufS/fillS stays.
__global__ __launch_bounds__(256) void pg_kernel(
    const int* __restrict__ src, const int* __restrict__ dst,
    int* __restrict__ gcurD, int* __restrict__ gcurS,
    int* __restrict__ gbufD, unsigned char* __restrict__ gbufS,
    const float* __restrict__ feat, const float* __restrict__ W1,
    unsigned short* __restrict__ h1, int E, int K, int PB, int N) {
    __shared__ char smem[16896];   // max(part 12.8 KB, gemm W1t 16.9 KB)
    const int t = threadIdx.x;

    if (blockIdx.x < PB) {
        // ---------------- part body (R0 form) ----------------
        int* cD = (int*)smem;
        int* bD = cD + 800;
        int* cS = bD + 800;
        int* bS = cS + 800;        // 3200 ints = 12.8 KB
        const int tile = blockIdx.x * TILE;
        for (int i = t; i < K; i += 256) { cD[i] = 0; cS[i] = 0; }
        __syncthreads();

        int dv[32];
        #pragma unroll
        for (int i = 0; i < 32; ++i) {
            const int e = tile + i * 256 + t;
            dv[i] = (e < E) ? dst[e] : -1;
            if (dv[i] >= 0) {
                atomicAdd(&cD[dv[i] >> BSHIFT], 1);
                atomicAdd(&cS[src[e] >> BSHIFT], 1);
            }
        }
        __syncthreads();
        for (int i = t; i < K; i += 256) {
            int c = cD[i];
            bD[i] = (c ? atomicAdd(&gcurD[i], c) : 0) + i * CAP;
            cD[i] = 0;
            c = cS[i];
            bS[i] = (c ? atomicAdd(&gcurS[i], c) : 0) + i * CAP;
            cS[i] = 0;
        }
        __syncthreads();
        #pragma unroll
        for (int i = 0; i < 32; ++i) {
            if (dv[i] >= 0) {
                const int e = tile + i * 256 + t;
                const int sv = src[e];
                const int b1 = dv[i] >> BSHIFT;
                const int p1 = bD[b1] + atomicAdd(&cD[b1], 1);
                gbufD[p1] = ((dv[i] & 127) << 17) | sv;
                const int b2 = sv >> BSHIFT;
                const int p2 = bS[b2] + atomicAdd(&cS[b2], 1);
                gbufS[p2] = (unsigned char)(sv & 127);
            }
        }
    } else {
        // ---------------- gemm1 body (unscaled h1) -------------------------
        short* W1t = (short*)smem;     // W1t[c][k] = bf16(W1[k][c]), stride 264
        for (int i = t; i < 8192; i += 256) {
            const int k = i >> 5, c = i & 31;
            W1t[c * 264 + k] = (short)f2bf(W1[i]);
        }
        __syncthreads();

        const int l  = t & 63;
        const int wv = t >> 6;
        const int base = (blockIdx.x - PB) * 128 + wv * 32;
        const int m  = l & 31;
        const int kh = (l >> 5) << 3;
        int r = base + m;
        if (r >= N) r = N - 1;
        const float* fr = feat + (size_t)r * 256 + kh;
        const short* wr = &W1t[m * 264 + kh];

        f32x16 acc;
        #pragma unroll
        for (int i = 0; i < 16; ++i) acc[i] = 0.f;

        #pragma unroll
        for (int kb = 0; kb < 16; ++kb) {
            const float4 f0 = *(const float4*)(fr + kb * 16);
            const float4 f1 = *(const float4*)(fr + kb * 16 + 4);
            bf16x8 a;
            a[0] = (short)f2bf(f0.x); a[1] = (short)f2bf(f0.y);
            a[2] = (short)f2bf(f0.z); a[3] = (short)f2bf(f0.w);
            a[4] = (short)f2bf(f1.x); a[5] = (short)f2bf(f1.y);
            a[6] = (short)f2bf(f1.z); a[7] = (short)f2bf(f1.w);
            const bf16x8 b = *(const bf16x8*)(wr + kb * 16);
            acc = __builtin_amdgcn_mfma_f32_32x32x16_bf16(a, b, acc, 0, 0, 0);
        }

        const int rbase = base + ((l >> 5) << 2);
        #pragma unroll
        for (int reg = 0; reg < 16; ++reg) {
            const int row = rbase + (reg & 3) + ((reg >> 2) << 3);
            if (row < N)
                h1[(size_t)row * 32 + m] = f2bf(acc[reg]);
        }
    }
}

// ---- fillS: per src-bucket (128 nodes): outdeg -> nsrc --------------------
__global__ __launch_bounds__(256) void fillS_kernel(
    const int* __restrict__ cntS, const unsigned char* __restrict__ gbufS,
    float* __restrict__ nsrc, int N, int K) {
    __shared__ int cnt[128];
    const int t = threadIdx.x;
    const int b = blockIdx.x;
    if (t < 128) cnt[t] = 0;
    __syncthreads();
    const int bs = b * CAP;
    const int be = bs + min(cntS[b], CAP);
    for (int idx = bs + t; idx < be; idx += 256)
        atomicAdd(&cnt[gbufS[idx]], 1);
    __syncthreads();
    const int n = (b << BSHIFT) + t;
    if (t < 128 && n < N) nsrc[n] = rsqrtf((float)cnt[t]);   // self-loops => deg>=1
}

// ---- fda1: fillD + agg1 fused, one 512-thread block per dst-bucket --------
// LDS sort (count/scan/scatter), CSR dumped in place over gbufD segment.
// R10 gather: 8 lanes/node edge-split -- two 4-lane groups (eg=0/1) take
// alternate 4-edge chunks, each unroll-4, merged via shfl_xor(4). In-flight
// loads per node 16->32, serial rounds ~9->~5, VGPR per lane unchanged.
// 512 thr / 8 lanes = 64 nodes per pass -> 2 passes over the 128 nodes.
__global__ __launch_bounds__(512) void fda1_kernel(
    const int* __restrict__ cntD, int* __restrict__ gbufD,
    const unsigned* __restrict__ h1, const float* __restrict__ nsrc,
    const float* __restrict__ b1, int* __restrict__ rowstart,
    int* __restrict__ indeg, float* __restrict__ ndst,
    unsigned* __restrict__ x1s, int N, int K) {
    __shared__ int lraw[CAP];          // 22.5 KB
    __shared__ int lcsr[CAP];          // 22.5 KB
    __shared__ int cnt[128], sc[128], cur[128];
    __shared__ float sb1[32];
    const int t = threadIdx.x;
    const int b = blockIdx.x;
    if (t < 128) cnt[t] = 0;
    if (t >= 128 && t < 160) sb1[t - 128] = b1[t - 128];
    __syncthreads();

    const int bs = b * CAP;
    const int total = min(cntD[b], CAP);   // defensive clamp (LDS bounds)
    for (int i = t; i < total; i += 512) {
        const int v = gbufD[bs + i];
        lraw[i] = v;
        atomicAdd(&cnt[v >> 17], 1);
    }
    __syncthreads();
    if (t < 128) sc[t] = cnt[t];
    __syncthreads();
    for (int off = 1; off < 128; off <<= 1) {
        int x = (t < 128 && t >= off) ? sc[t - off] : 0;
        __syncthreads();
        if (t < 128) sc[t] += x;
        __syncthreads();
    }
    if (t < 128) {
        const int deg = cnt[t];
        cur[t] = sc[t] - deg;          // bucket-local
        const int n = (b << BSHIFT) + t;
        if (n < N) {
            rowstart[n] = bs + sc[t] - deg;
            indeg[n] = deg;
            ndst[n] = rsqrtf((float)deg);   // self-loops => deg >= 1
        }
    }
    __syncthreads();
    for (int i = t; i < total; i += 512) {
        const int v = lraw[i];
        const int pos = atomicAdd(&cur[v >> 17], 1);
        lcsr[pos] = v & 131071;
    }
    __syncthreads();
    // dump sorted CSR for agg2f, in place over this bucket's gbufD segment
    for (int i = t; i < total; i += 512) gbufD[bs + i] = lcsr[i];

    // ---- agg1 from LDS csr: 8 lanes/node, 2 passes of 64 nodes ----
    const int c  = t & 3;
    const int eg = (t >> 2) & 1;
    const uint4* H = (const uint4*)h1;
    for (int half = 0; half < 2; ++half) {
        const int node = (t >> 3) + half * 64;
        const int n = (b << BSHIFT) + node;
        if (n >= N) continue;
        const int deg = cnt[node];
        const int re = sc[node];
        const int rs = re - deg;
        const int n8 = deg >> 3;
        float a0=0.f,a1=0.f,a2=0.f,a3=0.f,a4=0.f,a5=0.f,a6=0.f,a7=0.f;
        float d0=0.f,d1=0.f,d2=0.f,d3=0.f,d4=0.f,d5=0.f,d6=0.f,d7=0.f;
        for (int i = 0; i < n8; ++i) {
            const int k0 = rs + i * 8 + eg * 4;
            const int s0 = lcsr[k0],     s1 = lcsr[k0 + 1];
            const int s2 = lcsr[k0 + 2], s3 = lcsr[k0 + 3];
            const uint4 q0 = H[(size_t)s0 * 4 + c];
            const uint4 q1 = H[(size_t)s1 * 4 + c];
            const uint4 q2 = H[(size_t)s2 * 4 + c];
            const uint4 q3 = H[(size_t)s3 * 4 + c];
            const float w0 = nsrc[s0], w1 = nsrc[s1];
            const float w2 = nsrc[s2], w3 = nsrc[s3];
            a0 += bf_lo(q0.x)*w0; a1 += bf_hi(q0.x)*w0;
            a2 += bf_lo(q0.y)*w0; a3 += bf_hi(q0.y)*w0;
            a4 += bf_lo(q0.z)*w0; a5 += bf_hi(q0.z)*w0;
            a6 += bf_lo(q0.w)*w0; a7 += bf_hi(q0.w)*w0;
            d0 += bf_lo(q1.x)*w1; d1 += bf_hi(q1.x)*w1;
            d2 += bf_lo(q1.y)*w1; d3 += bf_hi(q1.y)*w1;
            d4 += bf_lo(q1.z)*w1; d5 += bf_hi(q1.z)*w1;
            d6 += bf_lo(q1.w)*w1; d7 += bf_hi(q1.w)*w1;
            a0 += bf_lo(q2.x)*w2; a1 += bf_hi(q2.x)*w2;
            a2 += bf_lo(q2.y)*w2; a3 += bf_hi(q2.y)*w2;
            a4 += bf_lo(q2.z)*w2; a5 += bf_hi(q2.z)*w2;
            a6 += bf_lo(q2.w)*w2; a7 += bf_hi(q2.w)*w2;
            d0 += bf_lo(q3.x)*w3; d1 += bf_hi(q3.x)*w3;
            d2 += bf_lo(q3.y)*w3; d3 += bf_hi(q3.y)*w3;
            d4 += bf_lo(q3.z)*w3; d5 += bf_hi(q3.z)*w3;
            d6 += bf_lo(q3.w)*w3; d7 += bf_hi(q3.w)*w3;
        }
        for (int k = rs + n8 * 8 + eg; k < re; k += 2) {
            const int s0 = lcsr[k];
            const uint4 q0 = H[(size_t)s0 * 4 + c];
            const float w0 = nsrc[s0];
            a0 += bf_lo(q0.x)*w0; a1 += bf_hi(q0.x)*w0;
            a2 += bf_lo(q0.y)*w0; a3 += bf_hi(q0.y)*w0;
            a4 += bf_lo(q0.z)*w0; a5 += bf_hi(q0.z)*w0;
            a6 += bf_lo(q0.w)*w0; a7 += bf_hi(q0.w)*w0;
        }
        a0 += d0; a1 += d1; a2 += d2; a3 += d3;
        a4 += d4; a5 += d5; a6 += d6; a7 += d7;
        // merge the two edge-groups (lanes t and t^4)
        a0 += __shfl_xor(a0, 4, 64); a1 += __shfl_xor(a1, 4, 64);
        a2 += __shfl_xor(a2, 4, 64); a3 += __shfl_xor(a3, 4, 64);
        a4 += __shfl_xor(a4, 4, 64); a5 += __shfl_xor(a5, 4, 64);
        a6 += __shfl_xor(a6, 4, 64); a7 += __shfl_xor(a7, 4, 64);
        if (eg == 0) {
            const float nd = rsqrtf((float)deg);
            const float ns = nsrc[n];
            const float* bb = sb1 + c * 8;
            float x0 = fmaxf(a0 * nd + bb[0], 0.f) * ns;
            float x1 = fmaxf(a1 * nd + bb[1], 0.f) * ns;
            float x2 = fmaxf(a2 * nd + bb[2], 0.f) * ns;
            float x3 = fmaxf(a3 * nd + bb[3], 0.f) * ns;
            float x4 = fmaxf(a4 * nd + bb[4], 0.f) * ns;
            float x5 = fmaxf(a5 * nd + bb[5], 0.f) * ns;
            float x6 = fmaxf(a6 * nd + bb[6], 0.f) * ns;
            float x7 = fmaxf(a7 * nd + bb[7], 0.f) * ns;
            uint4 o;
            o.x = packbf2(x0, x1); o.y = packbf2(x2, x3);
            o.z = packbf2(x4, x5); o.w = packbf2(x6, x7);
            ((uint4*)x1s)[(size_t)n * 4 + c] = o;
        }
    }
}

// ---- agg2+final fused: 8 lanes/node edge-split, 32 nodes/block ------------
// Same MLP restructure as fda1's gather. Epilogue re-split across 8 lanes:
// lane j = t&7 computes 5 logits (8 x 5 = 40), softmax via shfl_xor(1,2,4).
__global__ __launch_bounds__(256) void agg2f_kernel(
    const int* __restrict__ csr_src, const int* __restrict__ rowstart,
    const int* __restrict__ indeg, const unsigned* __restrict__ x1s,
    const float* __restrict__ ndst, const float* __restrict__ W2,
    const float* __restrict__ b2, float* __restrict__ out, int N) {
    __shared__ float sW2[32 * 40];
    __shared__ float sb2[40];
    const int t = threadIdx.x;
    for (int i = t; i < 1280; i += 256) sW2[i] = W2[i];
    if (t < 40) sb2[t] = b2[t];
    __syncthreads();
    const int n = blockIdx.x * 32 + (t >> 3);
    if (n >= N) return;
    const int c  = t & 3;
    const int eg = (t >> 2) & 1;
    const int rs = rowstart[n];
    const int deg = indeg[n];
    const int re = rs + deg;
    const int n8 = deg >> 3;
    float a0=0.f,a1=0.f,a2=0.f,a3=0.f,a4=0.f,a5=0.f,a6=0.f,a7=0.f;
    float d0=0.f,d1=0.f,d2=0.f,d3=0.f,d4=0.f,d5=0.f,d6=0.f,d7=0.f;
    const uint4* H = (const uint4*)x1s;
    for (int i = 0; i < n8; ++i) {
        const int k0 = rs + i * 8 + eg * 4;
        const int s0 = csr_src[k0],     s1 = csr_src[k0 + 1];
        const int s2 = csr_src[k0 + 2], s3 = csr_src[k0 + 3];
        const uint4 q0 = H[(size_t)s0 * 4 + c];
        const uint4 q1 = H[(size_t)s1 * 4 + c];
        const uint4 q2 = H[(size_t)s2 * 4 + c];
        const uint4 q3 = H[(size_t)s3 * 4 + c];
        a0 += bf_lo(q0.x); a1 += bf_hi(q0.x);
        a2 += bf_lo(q0.y); a3 += bf_hi(q0.y);
        a4 += bf_lo(q0.z); a5 += bf_hi(q0.z);
        a6 += bf_lo(q0.w); a7 += bf_hi(q0.w);
        d0 += bf_lo(q1.x); d1 += bf_hi(q1.x);
        d2 += bf_lo(q1.y); d3 += bf_hi(q1.y);
        d4 += bf_lo(q1.z); d5 += bf_hi(q1.z);
        d6 += bf_lo(q1.w); d7 += bf_hi(q1.w);
        a0 += bf_lo(q2.x); a1 += bf_hi(q2.x);
        a2 += bf_lo(q2.y); a3 += bf_hi(q2.y);
        a4 += bf_lo(q2.z); a5 += bf_hi(q2.z);
        a6 += bf_lo(q2.w); a7 += bf_hi(q2.w);
        d0 += bf_lo(q3.x); d1 += bf_hi(q3.x);
        d2 += bf_lo(q3.y); d3 += bf_hi(q3.y);
        d4 += bf_lo(q3.z); d5 += bf_hi(q3.z);
        d6 += bf_lo(q3.w); d7 += bf_hi(q3.w);
    }
    for (int k = rs + n8 * 8 + eg; k < re; k += 2) {
        const int s0 = csr_src[k];
        const uint4 q0 = H[(size_t)s0 * 4 + c];
        a0 += bf_lo(q0.x); a1 += bf_hi(q0.x);
        a2 += bf_lo(q0.y); a3 += bf_hi(q0.y);
        a4 += bf_lo(q0.z); a5 += bf_hi(q0.z);
        a6 += bf_lo(q0.w); a7 += bf_hi(q0.w);
    }
    a0 += d0; a1 += d1; a2 += d2; a3 += d3;
    a4 += d4; a5 += d5; a6 += d6; a7 += d7;
    a0 += __shfl_xor(a0, 4, 64); a1 += __shfl_xor(a1, 4, 64);
    a2 += __shfl_xor(a2, 4, 64); a3 += __shfl_xor(a3, 4, 64);
    a4 += __shfl_xor(a4, 4, 64); a5 += __shfl_xor(a5, 4, 64);
    a6 += __shfl_xor(a6, 4, 64); a7 += __shfl_xor(a7, 4, 64);
    const float nd = ndst[n];
    const float v0 = a0 * nd, v1 = a1 * nd, v2 = a2 * nd, v3 = a3 * nd;
    const float v4 = a4 * nd, v5 = a5 * nd, v6 = a6 * nd, v7 = a7 * nd;

    // lane j of the node's 8-lane group computes logits j*5 .. j*5+4.
    const int j = t & 7;
    float z[5];
    #pragma unroll
    for (int u = 0; u < 5; ++u) z[u] = sb2[j * 5 + u];
    const int gbase = (t & 63) & ~7;      // wave-lane base of this node's group
    #pragma unroll
    for (int cc = 0; cc < 4; ++cc) {
        const int sl = gbase + cc;        // lane holding channel-quarter cc
        const float w0 = __shfl(v0, sl, 64);
        const float w1 = __shfl(v1, sl, 64);
        const float w2 = __shfl(v2, sl, 64);
        const float w3 = __shfl(v3, sl, 64);
        const float w4 = __shfl(v4, sl, 64);
        const float w5 = __shfl(v5, sl, 64);
        const float w6 = __shfl(v6, sl, 64);
        const float w7 = __shfl(v7, sl, 64);
        const float* Wr = &sW2[(cc * 8) * 40 + j * 5];
        #pragma unroll
        for (int u = 0; u < 5; ++u) {
            z[u] += w0 * Wr[u]       + w1 * Wr[40 + u]  + w2 * Wr[80 + u]  + w3 * Wr[120 + u]
                  + w4 * Wr[160 + u] + w5 * Wr[200 + u] + w6 * Wr[240 + u] + w7 * Wr[280 + u];
        }
    }
    float m = z[0];
    #pragma unroll
    for (int u = 1; u < 5; ++u) m = fmaxf(m, z[u]);
    m = fmaxf(m, __shfl_xor(m, 1, 64));
    m = fmaxf(m, __shfl_xor(m, 2, 64));
    m = fmaxf(m, __shfl_xor(m, 4, 64));
    float s = 0.f;
    #pragma unroll
    for (int u = 0; u < 5; ++u) s += __expf(z[u] - m);
    s += __shfl_xor(s, 1, 64);
    s += __shfl_xor(s, 2, 64);
    s += __shfl_xor(s, 4, 64);
    const float ls = __logf(s);
    float* op = out + (size_t)n * 40 + j * 5;
    #pragma unroll
    for (int u = 0; u < 5; ++u) op[u] = z[u] - m - ls;
}

extern "C" void kernel_launch(void* const* d_in, const int* in_sizes, int n_in,
                              void* d_out, int out_size, void* d_ws, size_t ws_size,
                              hipStream_t stream) {
    const float* feat = (const float*)d_in[0];
    const int*   src  = (const int*)d_in[1];
    const int*   dst  = (const int*)d_in[2];
    const float* W1   = (const float*)d_in[3];
    const float* b1   = (const float*)d_in[4];
    const float* W2   = (const float*)d_in[5];
    const float* b2   = (const float*)d_in[6];
    float* out = (float*)d_out;

    const int N = in_sizes[0] / 256;   // 100000
    const int E = in_sizes[1];         // 3300000
    const int K = NBUCK(N);            // 782 buckets of 128 nodes

    // layout (R8 form). Overlays:
    //   csr_src == gbufD (same region): fda1 rewrites it in place with
    //   sorted CSR; agg2f reads the sorted version.
    //   gbufS (4.4 MB) -> over dead a2 region: read only by fillS.
    //   h1, x1s fully dedicated.
    char* p = (char*)d_ws;
    float* nsrc = (float*)p;                 p += (size_t)N * 4;        // 400 KB
    float* ndst = (float*)p;                 p += (size_t)N * 4;
    unsigned* h1  = (unsigned*)p;            p += (size_t)N * 64;       // 6.4 MB
    unsigned* x1s = (unsigned*)p;            p += (size_t)N * 64;       // 6.4 MB
    char* a2dead = (char*)p;                 p += (size_t)N * 128;      // 12.8 MB
    int* rowstart = (int*)p;                 p += (size_t)N * 4;
    int* indeg_i  = (int*)p;                 p += (size_t)N * 4;
    int* gcurD    = (int*)p;                 p += 800 * 4;
    int* gcurS    = (int*)p;                 p += 800 * 4;
    int* gbufD    = (int*)p;                 p += (size_t)K * CAP * 4;  // 17.6 MB, becomes csr
    unsigned char* gbufS = (unsigned char*)a2dead;   // 4.4 MB over dead a2

    hipMemsetAsync(gcurD, 0, sizeof(int) * 1600, stream);  // gcurD + gcurS

    const int PB = (E + TILE - 1) / TILE;      // 403 partition blocks
    const int GB = (N + 127) / 128;            // 782 gemm blocks

    pg_kernel<<<PB + GB, 256, 0, stream>>>(src, dst, gcurD, gcurS, gbufD, gbufS,
                                           feat, W1, (unsigned short*)h1, E, K, PB, N);
    fillS_kernel<<<K, 256, 0, stream>>>(gcurS, gbufS, nsrc, N, K);
    fda1_kernel<<<K, 512, 0, stream>>>(gcurD, gbufD, h1, nsrc, b1,
                                       rowstart, indeg_i, ndst, x1s, N, K);
    agg2f_kernel<<<(N + 31) / 32, 256, 0, stream>>>(gbufD, rowstart, indeg_i, x1s, ndst, W2, b2, out, N);
}

// Round 11
// 342.371 us; speedup vs baseline: 1.2047x; 1.0934x over previous
//
#include <hip/hip_runtime.h>
#include <hip/hip_bf16.h>
#include <math.h>

#define BSHIFT 7                 // 128 nodes per bucket
#define NBUCK(N) (((N) + 127) >> 7)
#define TILE 8192                // edges per partition block (R0 proven: 103 us)
#define CAP 5632                 // gbufD: max edges/bucket (mean 4224, ~21 sigma)
#define CAPS 2040                // gbufS: max edges/(bucket,XCD) (mean 528, ~3.9x)
#define NXCD 8

typedef short bf16x8 __attribute__((ext_vector_type(8)));
typedef float f32x16 __attribute__((ext_vector_type(16)));

// ---- bf16 helpers ---------------------------------------------------------
__device__ __forceinline__ unsigned short f2bf(float f) {
    unsigned u = __float_as_uint(f);
    u += 0x7fffu + ((u >> 16) & 1u);      // RNE
    return (unsigned short)(u >> 16);
}
__device__ __forceinline__ unsigned packbf2(float lo, float hi) {
    return (unsigned)f2bf(lo) | ((unsigned)f2bf(hi) << 16);
}
__device__ __forceinline__ float bf_lo(unsigned u) { return __uint_as_float(u << 16); }
__device__ __forceinline__ float bf_hi(unsigned u) { return __uint_as_float(u & 0xffff0000u); }

__device__ __forceinline__ int xcc_id() {
    int x;
    asm volatile("s_getreg_b32 %0, hwreg(HW_REG_XCC_ID)" : "=s"(x));
    return x & (NXCD - 1);
}

// ---- pg: part (blocks < PB) fused with gemm1 (blocks >= PB) ---------------
// R11: gbufS gets per-XCD windows. WRITE decomposition (R1/R9/R10) showed the
// 3.3M single-byte gbufS scatters cost ~150 MB in sector-RMW evictions (each
// 64B line = 64 entries written from ~6 XCDs -> ~6 partial evictions/line).
// Private (xcd,bucket) windows let each line accumulate in ONE L2 and evict
// ~once full. gbufD stays shared (16 entries/line ~ 1.5 blocks, amp ~1x).
__global__ __launch_bounds__(256) void pg_kernel(
    const int* __restrict__ src, const int* __restrict__ dst,
    int* __restrict__ gcurD, int* __restrict__ gcurS,
    int* __restrict__ gbufD, unsigned char* __restrict__ gbufS,
    const float* __restrict__ feat, const float* __restrict__ W1,
    unsigned short* __restrict__ h1, int E, int K, int PB, int N) {
    __shared__ char smem[16896];   // max(part 12.8 KB, gemm W1t 16.9 KB)
    const int t = threadIdx.x;

    if (blockIdx.x < PB) {
        // ---------------- part body ----------------
        int* cD = (int*)smem;
        int* bD = cD + 800;
        int* cS = bD + 800;
        int* bS = cS + 800;        // 3200 ints = 12.8 KB
        const int tile = blockIdx.x * TILE;
        const int vx = xcc_id();
        for (int i = t; i < K; i += 256) { cD[i] = 0; cS[i] = 0; }
        __syncthreads();

        int dv[32];
        #pragma unroll
        for (int i = 0; i < 32; ++i) {
            const int e = tile + i * 256 + t;
            dv[i] = (e < E) ? dst[e] : -1;
            if (dv[i] >= 0) {
                atomicAdd(&cD[dv[i] >> BSHIFT], 1);
                atomicAdd(&cS[src[e] >> BSHIFT], 1);
            }
        }
        __syncthreads();
        for (int i = t; i < K; i += 256) {
            int c = cD[i];
            bD[i] = (c ? atomicAdd(&gcurD[i], c) : 0) + i * CAP;
            cD[i] = 0;
            c = cS[i];
            bS[i] = (c ? atomicAdd(&gcurS[vx * K + i], c) : 0) + (vx * K + i) * CAPS;
            cS[i] = 0;
        }
        __syncthreads();
        #pragma unroll
        for (int i = 0; i < 32; ++i) {
            if (dv[i] >= 0) {
                const int e = tile + i * 256 + t;
                const int sv = src[e];
                const int b1 = dv[i] >> BSHIFT;
                const int p1 = bD[b1] + atomicAdd(&cD[b1], 1);
                gbufD[p1] = ((dv[i] & 127) << 17) | sv;
                const int b2 = sv >> BSHIFT;
                const int p2 = bS[b2] + atomicAdd(&cS[b2], 1);
                gbufS[p2] = (unsigned char)(sv & 127);
            }
        }
    } else {
        // ---------------- gemm1 body (unscaled h1) -------------------------
        short* W1t = (short*)smem;     // W1t[c][k] = bf16(W1[k][c]), stride 264
        for (int i = t; i < 8192; i += 256) {
            const int k = i >> 5, c = i & 31;
            W1t[c * 264 + k] = (short)f2bf(W1[i]);
        }
        __syncthreads();

        const int l  = t & 63;
        const int wv = t >> 6;
        const int base = (blockIdx.x - PB) * 128 + wv * 32;
        const int m  = l & 31;
        const int kh = (l >> 5) << 3;
        int r = base + m;
        if (r >= N) r = N - 1;
        const float* fr = feat + (size_t)r * 256 + kh;
        const short* wr = &W1t[m * 264 + kh];

        f32x16 acc;
        #pragma unroll
        for (int i = 0; i < 16; ++i) acc[i] = 0.f;

        #pragma unroll
        for (int kb = 0; kb < 16; ++kb) {
            const float4 f0 = *(const float4*)(fr + kb * 16);
            const float4 f1 = *(const float4*)(fr + kb * 16 + 4);
            bf16x8 a;
            a[0] = (short)f2bf(f0.x); a[1] = (short)f2bf(f0.y);
            a[2] = (short)f2bf(f0.z); a[3] = (short)f2bf(f0.w);
            a[4] = (short)f2bf(f1.x); a[5] = (short)f2bf(f1.y);
            a[6] = (short)f2bf(f1.z); a[7] = (short)f2bf(f1.w);
            const bf16x8 b = *(const bf16x8*)(wr + kb * 16);
            acc = __builtin_amdgcn_mfma_f32_32x32x16_bf16(a, b, acc, 0, 0, 0);
        }

        const int rbase = base + ((l >> 5) << 2);
        #pragma unroll
        for (int reg = 0; reg < 16; ++reg) {
            const int row = rbase + (reg & 3) + ((reg >> 2) << 3);
            if (row < N)
                h1[(size_t)row * 32 + m] = f2bf(acc[reg]);
        }
    }
}

// ---- fillS: outdeg -> nsrc, AND pre-scale this bucket's h1 rows by nsrc ---
// Bucket b owns CONTIGUOUS nodes [b*128,(b+1)*128) -> the h1 scale pass is an
// 8 KB coalesced read+write. This removes the per-edge nsrc[s] load from
// fda1's gather (halves its transaction count; aggs are rate-bound per R10).
// Cost: one extra bf16 rounding on h1 (monitor absmax).
__global__ __launch_bounds__(256) void fillS_kernel(
    const int* __restrict__ cntS, const unsigned char* __restrict__ gbufS,
    float* __restrict__ nsrc, unsigned* __restrict__ h1, int N, int K) {
    __shared__ int cnt[128];
    __shared__ float sns[128];
    const int t = threadIdx.x;
    const int b = blockIdx.x;
    if (t < 128) cnt[t] = 0;
    __syncthreads();
    for (int x = 0; x < NXCD; ++x) {
        const int seg = x * K + b;
        const int bs = seg * CAPS;
        const int be = bs + min(cntS[seg], CAPS);
        for (int idx = bs + t; idx < be; idx += 256)
            atomicAdd(&cnt[gbufS[idx]], 1);
    }
    __syncthreads();
    if (t < 128) {
        const float v = rsqrtf((float)cnt[t]);   // self-loops => deg>=1
        sns[t] = v;
        const int n = (b << BSHIFT) + t;
        if (n < N) nsrc[n] = v;
    }
    __syncthreads();
    // scale h1 rows in place: 2 threads/node x 8 u32 (row = 16 u32 = 64 B)
    const int node = t >> 1;
    const int n = (b << BSHIFT) + node;
    if (n < N) {
        const float ns = sns[node];
        unsigned* row = h1 + (size_t)n * 16 + (t & 1) * 8;
        uint4 q0 = *(uint4*)row;
        uint4 q1 = *(uint4*)(row + 4);
        q0.x = packbf2(bf_lo(q0.x) * ns, bf_hi(q0.x) * ns);
        q0.y = packbf2(bf_lo(q0.y) * ns, bf_hi(q0.y) * ns);
        q0.z = packbf2(bf_lo(q0.z) * ns, bf_hi(q0.z) * ns);
        q0.w = packbf2(bf_lo(q0.w) * ns, bf_hi(q0.w) * ns);
        q1.x = packbf2(bf_lo(q1.x) * ns, bf_hi(q1.x) * ns);
        q1.y = packbf2(bf_lo(q1.y) * ns, bf_hi(q1.y) * ns);
        q1.z = packbf2(bf_lo(q1.z) * ns, bf_hi(q1.z) * ns);
        q1.w = packbf2(bf_lo(q1.w) * ns, bf_hi(q1.w) * ns);
        *(uint4*)row = q0;
        *(uint4*)(row + 4) = q1;
    }
}

// ---- fda1: fillD + agg1 fused, one 512-thread block per dst-bucket --------
// LDS sort, CSR dumped in place over gbufD, gather 8 lanes/node edge-split.
// h1 is pre-scaled by nsrc (fillS) -> gather is pure adds, no nsrc loads.
__global__ __launch_bounds__(512) void fda1_kernel(
    const int* __restrict__ cntD, int* __restrict__ gbufD,
    const unsigned* __restrict__ h1, const float* __restrict__ nsrc,
    const float* __restrict__ b1, int* __restrict__ rowstart,
    int* __restrict__ indeg, float* __restrict__ ndst,
    unsigned* __restrict__ x1s, int N, int K) {
    __shared__ int lraw[CAP];          // 22.5 KB
    __shared__ int lcsr[CAP];          // 22.5 KB
    __shared__ int cnt[128], sc[128], cur[128];
    __shared__ float sb1[32];
    const int t = threadIdx.x;
    const int b = blockIdx.x;
    if (t < 128) cnt[t] = 0;
    if (t >= 128 && t < 160) sb1[t - 128] = b1[t - 128];
    __syncthreads();

    const int bs = b * CAP;
    const int total = min(cntD[b], CAP);   // defensive clamp (LDS bounds)
    for (int i = t; i < total; i += 512) {
        const int v = gbufD[bs + i];
        lraw[i] = v;
        atomicAdd(&cnt[v >> 17], 1);
    }
    __syncthreads();
    if (t < 128) sc[t] = cnt[t];
    __syncthreads();
    for (int off = 1; off < 128; off <<= 1) {
        int x = (t < 128 && t >= off) ? sc[t - off] : 0;
        __syncthreads();
        if (t < 128) sc[t] += x;
        __syncthreads();
    }
    if (t < 128) {
        const int deg = cnt[t];
        cur[t] = sc[t] - deg;          // bucket-local
        const int n = (b << BSHIFT) + t;
        if (n < N) {
            rowstart[n] = bs + sc[t] - deg;
            indeg[n] = deg;
            ndst[n] = rsqrtf((float)deg);   // self-loops => deg >= 1
        }
    }
    __syncthreads();
    for (int i = t; i < total; i += 512) {
        const int v = lraw[i];
        const int pos = atomicAdd(&cur[v >> 17], 1);
        lcsr[pos] = v & 131071;
    }
    __syncthreads();
    // dump sorted CSR for agg2f, in place over this bucket's gbufD segment
    for (int i = t; i < total; i += 512) gbufD[bs + i] = lcsr[i];

    // ---- agg1 from LDS csr: 8 lanes/node, 2 passes of 64 nodes ----
    const int c  = t & 3;
    const int eg = (t >> 2) & 1;
    const uint4* H = (const uint4*)h1;
    for (int half = 0; half < 2; ++half) {
        const int node = (t >> 3) + half * 64;
        const int n = (b << BSHIFT) + node;
        if (n >= N) continue;
        const int deg = cnt[node];
        const int re = sc[node];
        const int rs = re - deg;
        const int n8 = deg >> 3;
        float a0=0.f,a1=0.f,a2=0.f,a3=0.f,a4=0.f,a5=0.f,a6=0.f,a7=0.f;
        float d0=0.f,d1=0.f,d2=0.f,d3=0.f,d4=0.f,d5=0.f,d6=0.f,d7=0.f;
        for (int i = 0; i < n8; ++i) {
            const int k0 = rs + i * 8 + eg * 4;
            const int s0 = lcsr[k0],     s1 = lcsr[k0 + 1];
            const int s2 = lcsr[k0 + 2], s3 = lcsr[k0 + 3];
            const uint4 q0 = H[(size_t)s0 * 4 + c];
            const uint4 q1 = H[(size_t)s1 * 4 + c];
            const uint4 q2 = H[(size_t)s2 * 4 + c];
            const uint4 q3 = H[(size_t)s3 * 4 + c];
            a0 += bf_lo(q0.x); a1 += bf_hi(q0.x);
            a2 += bf_lo(q0.y); a3 += bf_hi(q0.y);
            a4 += bf_lo(q0.z); a5 += bf_hi(q0.z);
            a6 += bf_lo(q0.w); a7 += bf_hi(q0.w);
            d0 += bf_lo(q1.x); d1 += bf_hi(q1.x);
            d2 += bf_lo(q1.y); d3 += bf_hi(q1.y);
            d4 += bf_lo(q1.z); d5 += bf_hi(q1.z);
            d6 += bf_lo(q1.w); d7 += bf_hi(q1.w);
            a0 += bf_lo(q2.x); a1 += bf_hi(q2.x);
            a2 += bf_lo(q2.y); a3 += bf_hi(q2.y);
            a4 += bf_lo(q2.z); a5 += bf_hi(q2.z);
            a6 += bf_lo(q2.w); a7 += bf_hi(q2.w);
            d0 += bf_lo(q3.x); d1 += bf_hi(q3.x);
            d2 += bf_lo(q3.y); d3 += bf_hi(q3.y);
            d4 += bf_lo(q3.z); d5 += bf_hi(q3.z);
            d6 += bf_lo(q3.w); d7 += bf_hi(q3.w);
        }
        for (int k = rs + n8 * 8 + eg; k < re; k += 2) {
            const int s0 = lcsr[k];
            const uint4 q0 = H[(size_t)s0 * 4 + c];
            a0 += bf_lo(q0.x); a1 += bf_hi(q0.x);
            a2 += bf_lo(q0.y); a3 += bf_hi(q0.y);
            a4 += bf_lo(q0.z); a5 += bf_hi(q0.z);
            a6 += bf_lo(q0.w); a7 += bf_hi(q0.w);
        }
        a0 += d0; a1 += d1; a2 += d2; a3 += d3;
        a4 += d4; a5 += d5; a6 += d6; a7 += d7;
        // merge the two edge-groups (lanes t and t^4)
        a0 += __shfl_xor(a0, 4, 64); a1 += __shfl_xor(a1, 4, 64);
        a2 += __shfl_xor(a2, 4, 64); a3 += __shfl_xor(a3, 4, 64);
        a4 += __shfl_xor(a4, 4, 64); a5 += __shfl_xor(a5, 4, 64);
        a6 += __shfl_xor(a6, 4, 64); a7 += __shfl_xor(a7, 4, 64);
        if (eg == 0) {
            const float nd = rsqrtf((float)deg);
            const float ns = nsrc[n];
            const float* bb = sb1 + c * 8;
            float x0 = fmaxf(a0 * nd + bb[0], 0.f) * ns;
            float x1 = fmaxf(a1 * nd + bb[1], 0.f) * ns;
            float x2 = fmaxf(a2 * nd + bb[2], 0.f) * ns;
            float x3 = fmaxf(a3 * nd + bb[3], 0.f) * ns;
            float x4 = fmaxf(a4 * nd + bb[4], 0.f) * ns;
            float x5 = fmaxf(a5 * nd + bb[5], 0.f) * ns;
            float x6 = fmaxf(a6 * nd + bb[6], 0.f) * ns;
            float x7 = fmaxf(a7 * nd + bb[7], 0.f) * ns;
            uint4 o;
            o.x = packbf2(x0, x1); o.y = packbf2(x2, x3);
            o.z = packbf2(x4, x5); o.w = packbf2(x6, x7);
            ((uint4*)x1s)[(size_t)n * 4 + c] = o;
        }
    }
}

// ---- agg2+final fused: 8 lanes/node edge-split, 32 nodes/block ------------
__global__ __launch_bounds__(256) void agg2f_kernel(
    const int* __restrict__ csr_src, const int* __restrict__ rowstart,
    const int* __restrict__ indeg, const unsigned* __restrict__ x1s,
    const float* __restrict__ ndst, const float* __restrict__ W2,
    const float* __restrict__ b2, float* __restrict__ out, int N) {
    __shared__ float sW2[32 * 40];
    __shared__ float sb2[40];
    const int t = threadIdx.x;
    for (int i = t; i < 1280; i += 256) sW2[i] = W2[i];
    if (t < 40) sb2[t] = b2[t];
    __syncthreads();
    const int n = blockIdx.x * 32 + (t >> 3);
    if (n >= N) return;
    const int c  = t & 3;
    const int eg = (t >> 2) & 1;
    const int rs = rowstart[n];
    const int deg = indeg[n];
    const int re = rs + deg;
    const int n8 = deg >> 3;
    float a0=0.f,a1=0.f,a2=0.f,a3=0.f,a4=0.f,a5=0.f,a6=0.f,a7=0.f;
    float d0=0.f,d1=0.f,d2=0.f,d3=0.f,d4=0.f,d5=0.f,d6=0.f,d7=0.f;
    const uint4* H = (const uint4*)x1s;
    for (int i = 0; i < n8; ++i) {
        const int k0 = rs + i * 8 + eg * 4;
        const int s0 = csr_src[k0],     s1 = csr_src[k0 + 1];
        const int s2 = csr_src[k0 + 2], s3 = csr_src[k0 + 3];
        const uint4 q0 = H[(size_t)s0 * 4 + c];
        const uint4 q1 = H[(size_t)s1 * 4 + c];
        const uint4 q2 = H[(size_t)s2 * 4 + c];
        const uint4 q3 = H[(size_t)s3 * 4 + c];
        a0 += bf_lo(q0.x); a1 += bf_hi(q0.x);
        a2 += bf_lo(q0.y); a3 += bf_hi(q0.y);
        a4 += bf_lo(q0.z); a5 += bf_hi(q0.z);
        a6 += bf_lo(q0.w); a7 += bf_hi(q0.w);
        d0 += bf_lo(q1.x); d1 += bf_hi(q1.x);
        d2 += bf_lo(q1.y); d3 += bf_hi(q1.y);
        d4 += bf_lo(q1.z); d5 += bf_hi(q1.z);
        d6 += bf_lo(q1.w); d7 += bf_hi(q1.w);
        a0 += bf_lo(q2.x); a1 += bf_hi(q2.x);
        a2 += bf_lo(q2.y); a3 += bf_hi(q2.y);
        a4 += bf_lo(q2.z); a5 += bf_hi(q2.z);
        a6 += bf_lo(q2.w); a7 += bf_hi(q2.w);
        d0 += bf_lo(q3.x); d1 += bf_hi(q3.x);
        d2 += bf_lo(q3.y); d3 += bf_hi(q3.y);
        d4 += bf_lo(q3.z); d5 += bf_hi(q3.z);
        d6 += bf_lo(q3.w); d7 += bf_hi(q3.w);
    }
    for (int k = rs + n8 * 8 + eg; k < re; k += 2) {
        const int s0 = csr_src[k];
        const uint4 q0 = H[(size_t)s0 * 4 + c];
        a0 += bf_lo(q0.x); a1 += bf_hi(q0.x);
        a2 += bf_lo(q0.y); a3 += bf_hi(q0.y);
        a4 += bf_lo(q0.z); a5 += bf_hi(q0.z);
        a6 += bf_lo(q0.w); a7 += bf_hi(q0.w);
    }
    a0 += d0; a1 += d1; a2 += d2; a3 += d3;
    a4 += d4; a5 += d5; a6 += d6; a7 += d7;
    a0 += __shfl_xor(a0, 4, 64); a1 += __shfl_xor(a1, 4, 64);
    a2 += __shfl_xor(a2, 4, 64); a3 += __shfl_xor(a3, 4, 64);
    a4 += __shfl_xor(a4, 4, 64); a5 += __shfl_xor(a5, 4, 64);
    a6 += __shfl_xor(a6, 4, 64); a7 += __shfl_xor(a7, 4, 64);
    const float nd = ndst[n];
    const float v0 = a0 * nd, v1 = a1 * nd, v2 = a2 * nd, v3 = a3 * nd;
    const float v4 = a4 * nd, v5 = a5 * nd, v6 = a6 * nd, v7 = a7 * nd;

    // lane j of the node's 8-lane group computes logits j*5 .. j*5+4.
    const int j = t & 7;
    float z[5];
    #pragma unroll
    for (int u = 0; u < 5; ++u) z[u] = sb2[j * 5 + u];
    const int gbase = (t & 63) & ~7;      // wave-lane base of this node's group
    #pragma unroll
    for (int cc = 0; cc < 4; ++cc) {
        const int sl = gbase + cc;        // lane holding channel-quarter cc
        const float w0 = __shfl(v0, sl, 64);
        const float w1 = __shfl(v1, sl, 64);
        const float w2 = __shfl(v2, sl, 64);
        const float w3 = __shfl(v3, sl, 64);
        const float w4 = __shfl(v4, sl, 64);
        const float w5 = __shfl(v5, sl, 64);
        const float w6 = __shfl(v6, sl, 64);
        const float w7 = __shfl(v7, sl, 64);
        const float* Wr = &sW2[(cc * 8) * 40 + j * 5];
        #pragma unroll
        for (int u = 0; u < 5; ++u) {
            z[u] += w0 * Wr[u]       + w1 * Wr[40 + u]  + w2 * Wr[80 + u]  + w3 * Wr[120 + u]
                  + w4 * Wr[160 + u] + w5 * Wr[200 + u] + w6 * Wr[240 + u] + w7 * Wr[280 + u];
        }
    }
    float m = z[0];
    #pragma unroll
    for (int u = 1; u < 5; ++u) m = fmaxf(m, z[u]);
    m = fmaxf(m, __shfl_xor(m, 1, 64));
    m = fmaxf(m, __shfl_xor(m, 2, 64));
    m = fmaxf(m, __shfl_xor(m, 4, 64));
    float s = 0.f;
    #pragma unroll
    for (int u = 0; u < 5; ++u) s += __expf(z[u] - m);
    s += __shfl_xor(s, 1, 64);
    s += __shfl_xor(s, 2, 64);
    s += __shfl_xor(s, 4, 64);
    const float ls = __logf(s);
    float* op = out + (size_t)n * 40 + j * 5;
    #pragma unroll
    for (int u = 0; u < 5; ++u) op[u] = z[u] - m - ls;
}

extern "C" void kernel_launch(void* const* d_in, const int* in_sizes, int n_in,
                              void* d_out, int out_size, void* d_ws, size_t ws_size,
                              hipStream_t stream) {
    const float* feat = (const float*)d_in[0];
    const int*   src  = (const int*)d_in[1];
    const int*   dst  = (const int*)d_in[2];
    const float* W1   = (const float*)d_in[3];
    const float* b1   = (const float*)d_in[4];
    const float* W2   = (const float*)d_in[5];
    const float* b2   = (const float*)d_in[6];
    float* out = (float*)d_out;

    const int N = in_sizes[0] / 256;   // 100000
    const int E = in_sizes[1];         // 3300000
    const int K = NBUCK(N);            // 782 buckets of 128 nodes

    // layout (R8 form + per-XCD gcurS). Overlays:
    //   csr_src == gbufD (in-place sorted CSR, as R8).
    //   gbufS (NXCD*K*CAPS = 12.76 MB) -> over dead a2 region (12.8 MB).
    //   h1, x1s fully dedicated.
    char* p = (char*)d_ws;
    float* nsrc = (float*)p;                 p += (size_t)N * 4;        // 400 KB
    float* ndst = (float*)p;                 p += (size_t)N * 4;
    unsigned* h1  = (unsigned*)p;            p += (size_t)N * 64;       // 6.4 MB
    unsigned* x1s = (unsigned*)p;            p += (size_t)N * 64;       // 6.4 MB
    char* a2dead = (char*)p;                 p += (size_t)N * 128;      // 12.8 MB
    int* rowstart = (int*)p;                 p += (size_t)N * 4;
    int* indeg_i  = (int*)p;                 p += (size_t)N * 4;
    int* gcurD    = (int*)p;                 p += 800 * 4;
    int* gcurS    = (int*)p;                 p += (size_t)NXCD * 800 * 4;
    int* gbufD    = (int*)p;                 p += (size_t)K * CAP * 4;  // 17.6 MB, becomes csr
    unsigned char* gbufS = (unsigned char*)a2dead;   // 12.76 MB over dead a2

    hipMemsetAsync(gcurD, 0, sizeof(int) * (800 + NXCD * 800), stream);

    const int PB = (E + TILE - 1) / TILE;      // 403 partition blocks
    const int GB = (N + 127) / 128;            // 782 gemm blocks

    pg_kernel<<<PB + GB, 256, 0, stream>>>(src, dst, gcurD, gcurS, gbufD, gbufS,
                                           feat, W1, (unsigned short*)h1, E, K, PB, N);
    fillS_kernel<<<K, 256, 0, stream>>>(gcurS, gbufS, nsrc, h1, N, K);
    fda1_kernel<<<K, 512, 0, stream>>>(gcurD, gbufD, h1, nsrc, b1,
                                       rowstart, indeg_i, ndst, x1s, N, K);
    agg2f_kernel<<<(N + 31) / 32, 256, 0, stream>>>(gbufD, rowstart, indeg_i, x1s, ndst, W2, b2, out, N);
}